// Round 7
// baseline (81.650 us; speedup 1.0000x reference)
//
#include <hip/hip_runtime.h>
#include <math.h>
#include <stdint.h>

// NonLinearLayer: piecewise-quadratic CDF flow on a geometric mesh.
// x:(N,16) f32, pdj:(N,1), sldj:(N,1), log_p:(63,16), mesh_norm:(65,), elmt_size:(64,)
// out = concat(x_out (N*16), pdj_out (N), sldj_out (N))
//
// Bin index computed ANALYTICALLY (mesh geometric: boundary i at 1+K1*|x|=1.2^|i|).
// No searchsorted fixup: y and abs_det are continuous across bin boundaries.
//
// R7: R6 falsified the LDS-latency theory (forced asm batch, flat). New theory:
// memory-system efficiency — (a) per-wave MLP too low (32B outstanding/thread),
// (b) the 73MB store stream evicts x from L3 (FETCH=37MB on a 144MB working
// set in 256MB L3). Fix: 16 elems/thread (64B prefetch in flight) +
// NON-TEMPORAL stores so outputs don't churn the cache against x.

namespace {
constexpr int DIM = 16;
constexpr int ME  = 64;
constexpr float BOUNDF = 50.0f;
// K1 = 0.2/one_step = 0.02*(1.2^32-1);  INV_L2R = 1/log2(1.2)
constexpr float K1      = 6.8164378f;
constexpr float INV_L2R = 3.8017840f;
constexpr int COEF_FLOATS = ME * 68;                 // (A,B,D,2A)[bin][dim], stride 68 floats
constexpr int EP_BASE     = COEF_FLOATS - 63 * DIM;  // transient exp(log_p) scratch in tail
}

typedef float f32x4 __attribute__((ext_vector_type(4)));

__device__ __forceinline__ void nt_store4(float* p, float a, float b, float c, float d) {
  f32x4 v = {a, b, c, d};
  __builtin_nontemporal_store(v, reinterpret_cast<f32x4*>(p));
}

__global__ __launch_bounds__(256) void nll_kernel(
    const float* __restrict__ x,
    const float* __restrict__ pdj,
    const float* __restrict__ sldj,
    const float* __restrict__ log_p,
    const float* __restrict__ mesh_norm,
    float* __restrict__ out,
    int npts)
{
  __shared__ __align__(16) float co[COEF_FLOATS];
  __shared__ float s_mesh[ME + 1];

  const int tid = threadIdx.x;

  // ---- setup phase 1: loads + exp (fully parallel) ----
  if (tid <= ME) s_mesh[tid] = mesh_norm[tid];
  for (int i = tid; i < 63 * DIM; i += 256)
    co[EP_BASE + i] = __expf(log_p[i]);
  __syncthreads();

  // ---- setup phase 2a: stash ep columns in regs (scratch overwritten in 2b) ----
  const int wv = tid >> 6, lane = tid & 63;
  float epv[4];
#pragma unroll
  for (int i = 0; i < 4; ++i)
    epv[i] = (lane < 63) ? co[EP_BASE + lane * DIM + (4 * wv + i)] : 0.f;
  const float mj  = s_mesh[lane];
  const float mj1 = s_mesh[lane + 1];
  const float mj2 = s_mesh[(lane + 2 > ME) ? ME : (lane + 2)];
  const float es0 = s_mesh[1] - s_mesh[0];
  __syncthreads();

  // ---- setup phase 2b: wave-parallel normalize + prefix scan, 4 dims/wave ----
  const float h = mj1 - mj;
#pragma unroll
  for (int i = 0; i < 4; ++i) {
    const int d = 4 * wv + i;
    const float ep = epv[i];
    float ss = (lane < 63) ? ep * (mj2 - mj) : 0.f;
    ss += __shfl_xor(ss, 1);  ss += __shfl_xor(ss, 2);  ss += __shfl_xor(ss, 4);
    ss += __shfl_xor(ss, 8);  ss += __shfl_xor(ss, 16); ss += __shfl_xor(ss, 32);
    const float scale = (1.0f - es0) / (0.5f * ss);
    const float cur = (lane < 63) ? ep * scale : 1.0f;   // pdf_norm[lane+1]
    float prev = __shfl_up(cur, 1);                       // pdf_norm[lane]
    if (lane == 0) prev = 1.0f;
    const float cell = (prev + cur) * 0.5f * h;
    float v = cell, o;
    o = __shfl_up(v, 1);  if (lane >= 1)  v += o;
    o = __shfl_up(v, 2);  if (lane >= 2)  v += o;
    o = __shfl_up(v, 4);  if (lane >= 4)  v += o;
    o = __shfl_up(v, 8);  if (lane >= 8)  v += o;
    o = __shfl_up(v, 16); if (lane >= 16) v += o;
    o = __shfl_up(v, 32); if (lane >= 32) v += o;
    const float F = v - cell;                             // exclusive prefix = F_ref[lane]
    const float A = 0.5f * (cur - prev) / h;
    const float B = fmaf(-(A + A), mj, prev);
    const float D = fmaf(mj, fmaf(mj, A, -prev), F);
    *reinterpret_cast<float4*>(&co[lane * 68 + 4 * d]) = make_float4(A, B, D, A + A);
  }
  __syncthreads();

  // ---- main loop: one full point (16 dims) per thread, prefetched ----
  const int tpg = gridDim.x * blockDim.x;
  const float4* __restrict__ x4 = reinterpret_cast<const float4*>(x);
  const int np16 = npts * DIM;
  const uint32_t lds_base = (uint32_t)(uintptr_t)(&co[0]);  // low 32b of flat AS3 ptr == LDS offset

  int p = blockIdx.x * blockDim.x + tid;
  if (p >= npts) return;

  float4 X0 = x4[4 * p + 0], X1 = x4[4 * p + 1], X2 = x4[4 * p + 2], X3 = x4[4 * p + 3];
  float pv = pdj[p], sv = sldj[p];

  while (true) {
    const int pn = p + tpg;
    const bool more = pn < npts;

    // prefetch next point (64B/thread in flight under this iteration's work)
    float4 XN0, XN1, XN2, XN3;
    float pvn = 0.f, svn = 0.f;
    if (more) {
      XN0 = x4[4 * pn + 0]; XN1 = x4[4 * pn + 1];
      XN2 = x4[4 * pn + 2]; XN3 = x4[4 * pn + 3];
      pvn = pdj[pn]; svn = sldj[pn];
    }

    float vals[16];
    *reinterpret_cast<float4*>(&vals[0])  = X0;
    *reinterpret_cast<float4*>(&vals[4])  = X1;
    *reinterpret_cast<float4*>(&vals[8])  = X2;
    *reinterpret_cast<float4*>(&vals[12]) = X3;

    // phase A: 16 independent index chains
    float xn[16];
    uint32_t adr[16];
#pragma unroll
    for (int j = 0; j < 16; ++j) {
      const float val = vals[j];
      xn[j] = (val + BOUNDF) * 0.01f;
      const float u = fmaf(fabsf(val), K1, 1.0f);
      const float n = __log2f(u) * INV_L2R;
      int km1 = 31 + (int)ceilf(copysignf(n, val));
      km1 = km1 < 0 ? 0 : (km1 > 63 ? 63 : km1);
      adr[j] = lds_base + (uint32_t)((km1 * 68 + (j << 2)) << 2);
    }

    // phase B: 16 forced-in-flight ds_read_b128 gathers
    float4 c0, c1, c2, c3, c4, c5, c6, c7, c8, c9, cA, cB, cC, cD, cE, cF;
    asm volatile("ds_read_b128 %0, %1" : "=v"(c0) : "v"(adr[0]));
    asm volatile("ds_read_b128 %0, %1" : "=v"(c1) : "v"(adr[1]));
    asm volatile("ds_read_b128 %0, %1" : "=v"(c2) : "v"(adr[2]));
    asm volatile("ds_read_b128 %0, %1" : "=v"(c3) : "v"(adr[3]));
    asm volatile("ds_read_b128 %0, %1" : "=v"(c4) : "v"(adr[4]));
    asm volatile("ds_read_b128 %0, %1" : "=v"(c5) : "v"(adr[5]));
    asm volatile("ds_read_b128 %0, %1" : "=v"(c6) : "v"(adr[6]));
    asm volatile("ds_read_b128 %0, %1" : "=v"(c7) : "v"(adr[7]));
    asm volatile("ds_read_b128 %0, %1" : "=v"(c8) : "v"(adr[8]));
    asm volatile("ds_read_b128 %0, %1" : "=v"(c9) : "v"(adr[9]));
    asm volatile("ds_read_b128 %0, %1" : "=v"(cA) : "v"(adr[10]));
    asm volatile("ds_read_b128 %0, %1" : "=v"(cB) : "v"(adr[11]));
    asm volatile("ds_read_b128 %0, %1" : "=v"(cC) : "v"(adr[12]));
    asm volatile("ds_read_b128 %0, %1" : "=v"(cD) : "v"(adr[13]));
    asm volatile("ds_read_b128 %0, %1" : "=v"(cE) : "v"(adr[14]));
    asm volatile("ds_read_b128 %0, %1" : "=v"(cF) : "v"(adr[15]));

    float yv[16], dt[16];
    // front half: wait until first 8 done (8 may remain outstanding)
    asm volatile("s_waitcnt lgkmcnt(8)" ::: "memory");
    __builtin_amdgcn_sched_barrier(0);
    {
      const float4 cfh[8] = {c0, c1, c2, c3, c4, c5, c6, c7};
#pragma unroll
      for (int j = 0; j < 8; ++j) {
        const float z = xn[j];
        float y = fmaf(z, fmaf(z, cfh[j].x, cfh[j].y), cfh[j].z);
        float d = fmaf(z, cfh[j].w, cfh[j].y);
        const bool cover = (z > 0.f) && (z <= 1.0f);
        yv[j] = fmaf(cover ? y : z, 2.0f * BOUNDF, -BOUNDF);
        dt[j] = cover ? d : 1.0f;
      }
    }
    asm volatile("s_waitcnt lgkmcnt(0)" ::: "memory");
    __builtin_amdgcn_sched_barrier(0);
    {
      const float4 cfh[8] = {c8, c9, cA, cB, cC, cD, cE, cF};
#pragma unroll
      for (int j = 0; j < 8; ++j) {
        const float z = xn[8 + j];
        float y = fmaf(z, fmaf(z, cfh[j].x, cfh[j].y), cfh[j].z);
        float d = fmaf(z, cfh[j].w, cfh[j].y);
        const bool cover = (z > 0.f) && (z <= 1.0f);
        yv[8 + j] = fmaf(cover ? y : z, 2.0f * BOUNDF, -BOUNDF);
        dt[8 + j] = cover ? d : 1.0f;
      }
    }

    const float prod = (((dt[0] * dt[1]) * (dt[2] * dt[3])) *
                        ((dt[4] * dt[5]) * (dt[6] * dt[7]))) *
                       (((dt[8] * dt[9]) * (dt[10] * dt[11])) *
                        ((dt[12] * dt[13]) * (dt[14] * dt[15])));

    // non-temporal streaming stores (outputs never re-read in-dispatch)
    float* ob = out + 16 * p;
    nt_store4(ob + 0,  yv[0],  yv[1],  yv[2],  yv[3]);
    nt_store4(ob + 4,  yv[4],  yv[5],  yv[6],  yv[7]);
    nt_store4(ob + 8,  yv[8],  yv[9],  yv[10], yv[11]);
    nt_store4(ob + 12, yv[12], yv[13], yv[14], yv[15]);
    __builtin_nontemporal_store(pv * prod, out + np16 + p);
    __builtin_nontemporal_store(sv + __logf(prod), out + np16 + npts + p);

    if (!more) break;
    p = pn; X0 = XN0; X1 = XN1; X2 = XN2; X3 = XN3; pv = pvn; sv = svn;
  }
}

extern "C" void kernel_launch(void* const* d_in, const int* in_sizes, int n_in,
                              void* d_out, int out_size, void* d_ws, size_t ws_size,
                              hipStream_t stream) {
  const float* x    = (const float*)d_in[0];
  const float* pdj  = (const float*)d_in[1];
  const float* sldj = (const float*)d_in[2];
  const float* lp   = (const float*)d_in[3];
  const float* mesh = (const float*)d_in[4];
  float* out = (float*)d_out;

  const int npts  = in_sizes[0] / DIM;
  const int block = 256;
  int grid = 2048;
  const int needed = (npts + block - 1) / block;
  if (needed < grid) grid = needed;

  hipLaunchKernelGGL(nll_kernel, dim3(grid), dim3(block), 0, stream,
                     x, pdj, sldj, lp, mesh, out, npts);
}

// Round 8
// 32.848 us; speedup vs baseline: 2.4857x; 2.4857x over previous
//
#include <hip/hip_runtime.h>
#include <math.h>
#include <stdint.h>

// NonLinearLayer: piecewise-quadratic CDF flow on a geometric mesh.
// x:(N,16) f32, pdj:(N,1), sldj:(N,1), log_p:(63,16), mesh_norm:(65,), elmt_size:(64,)
// out = concat(x_out (N*16), pdj_out (N), sldj_out (N))
//
// Bin index computed ANALYTICALLY (mesh geometric: boundary i at 1+K1*|x|=1.2^|i|).
// No searchsorted fixup (continuity makes +-1 boundary misclassification ~1e-5).
//
// R8: R4 structure (8 elem/thread, coalesced float4 cached stores) +
//  - SENTINEL BINS: rows 0 and 65 hold (A,B,D,2A)=(0,1,0,0) so the quadratic
//    evaluates exactly to the uncovered path (y=xn, dt=1). No cover compares,
//    no selects; index = clamp(searchsorted k, 0, 65) straight into the table.
//  - depth-2 global prefetch (t+2*tpg in flight while computing t).
// R7 lessons locked in: NO non-temporal stores (2.2x write amplification),
// lane-interleaved store layout only.

namespace {
constexpr int DIM = 16;
constexpr int ME  = 64;
constexpr float BOUNDF = 50.0f;
// K1 = 0.2/one_step = 0.02*(1.2^32-1);  INV_L2R = 1/log2(1.2)
constexpr float K1      = 6.8164378f;
constexpr float INV_L2R = 3.8017840f;
constexpr int NBIN = 66;                       // sentinel 0, real 1..64, sentinel 65
constexpr int ROWF = 68;                       // floats per row: 16 dims * 4 + pad
constexpr int COEF_FLOATS = NBIN * ROWF;       // 4488
constexpr int EP_BASE = COEF_FLOATS - 63 * DIM; // 3480: transient exp(log_p) scratch
}

__global__ __launch_bounds__(256) void nll_kernel(
    const float* __restrict__ x,
    const float* __restrict__ pdj,
    const float* __restrict__ sldj,
    const float* __restrict__ log_p,
    const float* __restrict__ mesh_norm,
    float* __restrict__ out,
    int npts, int npairs)
{
  __shared__ __align__(16) float co[COEF_FLOATS];
  __shared__ float s_mesh[ME + 1];

  const int tid = threadIdx.x;

  // ---- setup 1: parallel loads + exp ----
  if (tid <= ME) s_mesh[tid] = mesh_norm[tid];
  for (int i = tid; i < 63 * DIM; i += 256)
    co[EP_BASE + i] = __expf(log_p[i]);
  __syncthreads();

  // ---- setup 2a: stash ep columns in regs (scratch overwritten in 2b) ----
  const int wv = tid >> 6, lane = tid & 63;
  float epv[4];
#pragma unroll
  for (int i = 0; i < 4; ++i)
    epv[i] = (lane < 63) ? co[EP_BASE + lane * DIM + (4 * wv + i)] : 0.f;
  const float mj  = s_mesh[lane];
  const float mj1 = s_mesh[lane + 1];
  const float mj2 = s_mesh[(lane + 2 > ME) ? ME : (lane + 2)];
  const float es0 = s_mesh[1] - s_mesh[0];
  __syncthreads();

  // ---- setup 2b: wave-parallel normalize + prefix scan, 4 dims/wave.
  //      lane l writes table row l+1 (row = searchsorted k). ----
  const float h = mj1 - mj;
#pragma unroll
  for (int i = 0; i < 4; ++i) {
    const int d = 4 * wv + i;
    const float ep = epv[i];
    float ss = (lane < 63) ? ep * (mj2 - mj) : 0.f;
    ss += __shfl_xor(ss, 1);  ss += __shfl_xor(ss, 2);  ss += __shfl_xor(ss, 4);
    ss += __shfl_xor(ss, 8);  ss += __shfl_xor(ss, 16); ss += __shfl_xor(ss, 32);
    const float scale = (1.0f - es0) / (0.5f * ss);
    const float cur = (lane < 63) ? ep * scale : 1.0f;   // pdf_norm[lane+1]
    float prev = __shfl_up(cur, 1);                       // pdf_norm[lane]
    if (lane == 0) prev = 1.0f;
    const float cell = (prev + cur) * 0.5f * h;
    float v = cell, o;
    o = __shfl_up(v, 1);  if (lane >= 1)  v += o;
    o = __shfl_up(v, 2);  if (lane >= 2)  v += o;
    o = __shfl_up(v, 4);  if (lane >= 4)  v += o;
    o = __shfl_up(v, 8);  if (lane >= 8)  v += o;
    o = __shfl_up(v, 16); if (lane >= 16) v += o;
    o = __shfl_up(v, 32); if (lane >= 32) v += o;
    const float F = v - cell;                             // exclusive prefix = F_ref[lane]
    const float A = 0.5f * (cur - prev) / h;
    const float B = fmaf(-(A + A), mj, prev);
    const float D = fmaf(mj, fmaf(mj, A, -prev), F);
    *reinterpret_cast<float4*>(&co[(lane + 1) * ROWF + 4 * d]) = make_float4(A, B, D, A + A);
  }
  // sentinel rows 0 and 65: (A,B,D,2A) = (0,1,0,0) -> y=xn, dt=1 exactly
  if (tid < 32) {
    const int row = (tid >> 4) ? (NBIN - 1) : 0;
    const int d = tid & 15;
    *reinterpret_cast<float4*>(&co[row * ROWF + 4 * d]) = make_float4(0.f, 1.f, 0.f, 0.f);
  }
  __syncthreads();

  // ---- main loop: 8 elems (half point) per thread, depth-2 prefetch ----
  const int tpg = gridDim.x * blockDim.x;
  const float4* __restrict__ x4 = reinterpret_cast<const float4*>(x);
  float4* __restrict__ out4 = reinterpret_cast<float4*>(out);
  const int np16 = npts * DIM;

  int t = blockIdx.x * blockDim.x + tid;
  if (t >= npairs) return;

  // pipeline stage A (current) and B (next)
  float4 a0 = x4[2 * t], a1 = x4[2 * t + 1];
  float aps = (t & 1) ? sldj[t >> 1] : pdj[t >> 1];
  int tB = t + tpg;
  bool hasB = tB < npairs;
  float4 b0, b1; float bps = 0.f;
  if (hasB) {
    b0 = x4[2 * tB]; b1 = x4[2 * tB + 1];
    bps = (tB & 1) ? sldj[tB >> 1] : pdj[tB >> 1];
  }

  while (true) {
    // prefetch stage C (t + 2*tpg) — has ~2 iterations to land
    const int tC = t + 2 * tpg;
    const bool hasC = tC < npairs;
    float4 c0, c1; float cps = 0.f;
    if (hasC) {
      c0 = x4[2 * tC]; c1 = x4[2 * tC + 1];
      cps = (tC & 1) ? sldj[tC >> 1] : pdj[tC >> 1];
    }

    // ---- compute current (t, a0, a1, aps) ----
    const int p  = t >> 1;
    const int hh = t & 1;                      // half: dims hh*8 .. hh*8+7
    const int dbase = hh << 5;                 // float offset of dim block in a row
    const float vals[8] = {a0.x, a0.y, a0.z, a0.w, a1.x, a1.y, a1.z, a1.w};

    float xn[8];
    int   idx[8];
#pragma unroll
    for (int j = 0; j < 8; ++j) {
      const float val = vals[j];
      xn[j] = fmaf(val, 0.01f, 0.5f);
      const float u = fmaf(fabsf(val), K1, 1.0f);
      const float n = __log2f(u) * INV_L2R;
      int k = 32 + (int)ceilf(copysignf(n, val));   // searchsorted k
      k = k < 0 ? 0 : (k > NBIN - 1 ? NBIN - 1 : k);
      idx[j] = k * ROWF + dbase + (j << 2);
    }

    float4 cf[8];
#pragma unroll
    for (int j = 0; j < 8; ++j)
      cf[j] = *reinterpret_cast<const float4*>(&co[idx[j]]);

    float yv[8], dt[8];
#pragma unroll
    for (int j = 0; j < 8; ++j) {
      const float z = xn[j];
      yv[j] = fmaf(fmaf(z, fmaf(z, cf[j].x, cf[j].y), cf[j].z), 2.0f * BOUNDF, -BOUNDF);
      dt[j] = fmaf(z, cf[j].w, cf[j].y);
    }
    const float prod = ((dt[0] * dt[1]) * (dt[2] * dt[3])) *
                       ((dt[4] * dt[5]) * (dt[6] * dt[7]));

    out4[2 * t]     = make_float4(yv[0], yv[1], yv[2], yv[3]);
    out4[2 * t + 1] = make_float4(yv[4], yv[5], yv[6], yv[7]);

    const float full = prod * __shfl_xor(prod, 1);
    const float res  = hh ? (aps + __logf(full)) : (aps * full);
    out[np16 + hh * npts + p] = res;

    if (!hasB) break;
    t = tB; a0 = b0; a1 = b1; aps = bps;
    tB = tC; hasB = hasC; b0 = c0; b1 = c1; bps = cps;
  }
}

extern "C" void kernel_launch(void* const* d_in, const int* in_sizes, int n_in,
                              void* d_out, int out_size, void* d_ws, size_t ws_size,
                              hipStream_t stream) {
  const float* x    = (const float*)d_in[0];
  const float* pdj  = (const float*)d_in[1];
  const float* sldj = (const float*)d_in[2];
  const float* lp   = (const float*)d_in[3];
  const float* mesh = (const float*)d_in[4];
  float* out = (float*)d_out;

  const int npts   = in_sizes[0] / DIM;
  const int npairs = npts * 2;
  const int block  = 256;
  int grid = 2048;
  const int needed = (npairs + block - 1) / block;
  if (needed < grid) grid = needed;

  hipLaunchKernelGGL(nll_kernel, dim3(grid), dim3(block), 0, stream,
                     x, pdj, sldj, lp, mesh, out, npts, npairs);
}

// Round 9
// 32.682 us; speedup vs baseline: 2.4983x; 1.0051x over previous
//
#include <hip/hip_runtime.h>
#include <math.h>
#include <stdint.h>

// NonLinearLayer: piecewise-quadratic CDF flow on a geometric mesh.
// x:(N,16) f32, pdj:(N,1), sldj:(N,1), log_p:(63,16), mesh_norm:(65,), elmt_size:(64,)
// out = concat(x_out (N*16), pdj_out (N), sldj_out (N))
//
// R9: R8 + ASM-PINNED global prefetch. R8's C-level depth-2 prefetch was sunk
// back to load-at-use (VGPR stuck at 32) => each wave had only ~32B reads in
// flight at <50% duty => read-MLP bound (Little's law: need ~1KB/CU at 400-900
// cyc latency). Volatile-asm loads into pinned regs can't be sunk; manual 2x
// unrolled ping-pong avoids copying in-flight registers. vmcnt(6) per in-order
// retirement: [wanted(3) oldest | 3 stores | 3 newer loads]. "memory" clobber
// on the wait keeps stores from sinking past it. launch_bounds(256,8) caps
// VGPR at 64 -> 8 blocks/CU (LDS 18.4KB*8=147KB) = 32 waves/CU.

namespace {
constexpr int DIM = 16;
constexpr int ME  = 64;
constexpr float BOUNDF = 50.0f;
// K1 = 0.2/one_step = 0.02*(1.2^32-1);  INV_L2R = 1/log2(1.2)
constexpr float K1      = 6.8164378f;
constexpr float INV_L2R = 3.8017840f;
constexpr int NBIN = 66;                       // sentinel 0, real 1..64, sentinel 65
constexpr int ROWF = 68;                       // floats per row: 16 dims * 4 + pad
constexpr int COEF_FLOATS = NBIN * ROWF;       // 4488
constexpr int EP_BASE = COEF_FLOATS - 63 * DIM; // transient exp(log_p) scratch
}

__global__ __launch_bounds__(256, 8) void nll_kernel(
    const float* __restrict__ x,
    const float* __restrict__ pdj,
    const float* __restrict__ sldj,
    const float* __restrict__ log_p,
    const float* __restrict__ mesh_norm,
    float* __restrict__ out,
    int npts, int npairs)
{
  __shared__ __align__(16) float co[COEF_FLOATS];
  __shared__ float s_mesh[ME + 1];

  const int tid = threadIdx.x;

  // ---- setup 1: parallel loads + exp ----
  if (tid <= ME) s_mesh[tid] = mesh_norm[tid];
  for (int i = tid; i < 63 * DIM; i += 256)
    co[EP_BASE + i] = __expf(log_p[i]);
  __syncthreads();

  // ---- setup 2a: stash ep columns in regs (scratch overwritten in 2b) ----
  const int wv = tid >> 6, lane = tid & 63;
  float epv[4];
#pragma unroll
  for (int i = 0; i < 4; ++i)
    epv[i] = (lane < 63) ? co[EP_BASE + lane * DIM + (4 * wv + i)] : 0.f;
  const float mj  = s_mesh[lane];
  const float mj1 = s_mesh[lane + 1];
  const float mj2 = s_mesh[(lane + 2 > ME) ? ME : (lane + 2)];
  const float es0 = s_mesh[1] - s_mesh[0];
  __syncthreads();

  // ---- setup 2b: wave-parallel normalize + prefix scan, 4 dims/wave.
  //      lane l writes table row l+1 (row = searchsorted k). ----
  const float h = mj1 - mj;
#pragma unroll
  for (int i = 0; i < 4; ++i) {
    const int d = 4 * wv + i;
    const float ep = epv[i];
    float ss = (lane < 63) ? ep * (mj2 - mj) : 0.f;
    ss += __shfl_xor(ss, 1);  ss += __shfl_xor(ss, 2);  ss += __shfl_xor(ss, 4);
    ss += __shfl_xor(ss, 8);  ss += __shfl_xor(ss, 16); ss += __shfl_xor(ss, 32);
    const float scale = (1.0f - es0) / (0.5f * ss);
    const float cur = (lane < 63) ? ep * scale : 1.0f;   // pdf_norm[lane+1]
    float prev = __shfl_up(cur, 1);                       // pdf_norm[lane]
    if (lane == 0) prev = 1.0f;
    const float cell = (prev + cur) * 0.5f * h;
    float v = cell, o;
    o = __shfl_up(v, 1);  if (lane >= 1)  v += o;
    o = __shfl_up(v, 2);  if (lane >= 2)  v += o;
    o = __shfl_up(v, 4);  if (lane >= 4)  v += o;
    o = __shfl_up(v, 8);  if (lane >= 8)  v += o;
    o = __shfl_up(v, 16); if (lane >= 16) v += o;
    o = __shfl_up(v, 32); if (lane >= 32) v += o;
    const float F = v - cell;                             // exclusive prefix = F_ref[lane]
    const float A = 0.5f * (cur - prev) / h;
    const float B = fmaf(-(A + A), mj, prev);
    const float D = fmaf(mj, fmaf(mj, A, -prev), F);
    *reinterpret_cast<float4*>(&co[(lane + 1) * ROWF + 4 * d]) = make_float4(A, B, D, A + A);
  }
  // sentinel rows 0 and 65: (A,B,D,2A) = (0,1,0,0) -> y=xn, dt=1 exactly
  if (tid < 32) {
    const int row = (tid >> 4) ? (NBIN - 1) : 0;
    const int d = tid & 15;
    *reinterpret_cast<float4*>(&co[row * ROWF + 4 * d]) = make_float4(0.f, 1.f, 0.f, 0.f);
  }
  __syncthreads();

  // ---- main loop: 8 elems (half point)/thread; asm-pinned ping-pong prefetch ----
  const int tpg = gridDim.x * blockDim.x;
  const float4* __restrict__ x4 = reinterpret_cast<const float4*>(x);
  float4* __restrict__ out4 = reinterpret_cast<float4*>(out);
  const int np16 = npts * DIM;

  int t = blockIdx.x * blockDim.x + tid;
  if (t >= npairs) return;

  // issue next-tile loads into pinned regs (clamped OOB -> reload current)
#define ISSUE_TILE(TT, XA, XB, PS)                                            \
  {                                                                           \
    const float4* xs_ = x4 + 2 * (TT);                                        \
    const float* ss_ = (((TT) & 1) ? sldj : pdj) + ((TT) >> 1);               \
    asm volatile("global_load_dwordx4 %0, %1, off" : "=v"(XA) : "v"(xs_));    \
    asm volatile("global_load_dwordx4 %0, %1, off" : "=v"(XB) : "v"(xs_ + 1));\
    asm volatile("global_load_dword %0, %1, off"   : "=v"(PS) : "v"(ss_));    \
  }

  // compute + store one tile (3 stores: 2x dwordx4 + 1 dword)
#define COMPUTE_TILE(TT, XA, XB, PS)                                          \
  {                                                                           \
    const int p_  = (TT) >> 1;                                                \
    const int hh_ = (TT) & 1;                                                 \
    const int dbase_ = hh_ << 5;                                              \
    const float vals_[8] = {(XA).x, (XA).y, (XA).z, (XA).w,                   \
                            (XB).x, (XB).y, (XB).z, (XB).w};                  \
    float xn_[8]; int idx_[8];                                                \
    _Pragma("unroll")                                                         \
    for (int j = 0; j < 8; ++j) {                                             \
      const float val_ = vals_[j];                                            \
      xn_[j] = fmaf(val_, 0.01f, 0.5f);                                       \
      const float u_ = fmaf(fabsf(val_), K1, 1.0f);                           \
      const float n_ = __log2f(u_) * INV_L2R;                                 \
      int k_ = 32 + (int)ceilf(copysignf(n_, val_));                          \
      k_ = k_ < 0 ? 0 : (k_ > NBIN - 1 ? NBIN - 1 : k_);                      \
      idx_[j] = k_ * ROWF + dbase_ + (j << 2);                                \
    }                                                                         \
    float4 cf_[8];                                                            \
    _Pragma("unroll")                                                         \
    for (int j = 0; j < 8; ++j)                                               \
      cf_[j] = *reinterpret_cast<const float4*>(&co[idx_[j]]);                \
    float yv_[8], dt_[8];                                                     \
    _Pragma("unroll")                                                         \
    for (int j = 0; j < 8; ++j) {                                             \
      const float z_ = xn_[j];                                                \
      yv_[j] = fmaf(fmaf(z_, fmaf(z_, cf_[j].x, cf_[j].y), cf_[j].z),         \
                    2.0f * BOUNDF, -BOUNDF);                                  \
      dt_[j] = fmaf(z_, cf_[j].w, cf_[j].y);                                  \
    }                                                                         \
    const float prod_ = ((dt_[0] * dt_[1]) * (dt_[2] * dt_[3])) *             \
                        ((dt_[4] * dt_[5]) * (dt_[6] * dt_[7]));              \
    out4[2 * (TT)]     = make_float4(yv_[0], yv_[1], yv_[2], yv_[3]);         \
    out4[2 * (TT) + 1] = make_float4(yv_[4], yv_[5], yv_[6], yv_[7]);         \
    const float full_ = prod_ * __shfl_xor(prod_, 1);                         \
    const float res_  = hh_ ? ((PS) + __logf(full_)) : ((PS) * full_);        \
    out[np16 + hh_ * npts + p_] = res_;                                       \
  }

#define WAIT_PINNED()                                                         \
  asm volatile("s_waitcnt vmcnt(6)" ::: "memory");                            \
  __builtin_amdgcn_sched_barrier(0);

  // prologue: tile A via compiler loads (compiler inserts its own waits)
  float4 a0 = x4[2 * t], a1 = x4[2 * t + 1];
  float aps = (t & 1) ? sldj[t >> 1] : pdj[t >> 1];
  float4 b0, b1; float bps;
  {
    const int tn = (t + tpg < npairs) ? t + tpg : t;
    ISSUE_TILE(tn, b0, b1, bps);
  }

  for (;;) {
    COMPUTE_TILE(t, a0, a1, aps);
    int t1 = t + tpg;
    if (t1 >= npairs) break;
    {
      const int tn = (t1 + tpg < npairs) ? t1 + tpg : t1;
      ISSUE_TILE(tn, a0, a1, aps);          // reuse A regs for tile t1+tpg
    }
    WAIT_PINNED();                          // B's loads (oldest 3 of <=9) landed

    COMPUTE_TILE(t1, b0, b1, bps);
    t = t1 + tpg;
    if (t >= npairs) break;
    {
      const int tn = (t + tpg < npairs) ? t + tpg : t;
      ISSUE_TILE(tn, b0, b1, bps);
    }
    WAIT_PINNED();                          // A's loads landed
  }
#undef ISSUE_TILE
#undef COMPUTE_TILE
#undef WAIT_PINNED
}

extern "C" void kernel_launch(void* const* d_in, const int* in_sizes, int n_in,
                              void* d_out, int out_size, void* d_ws, size_t ws_size,
                              hipStream_t stream) {
  const float* x    = (const float*)d_in[0];
  const float* pdj  = (const float*)d_in[1];
  const float* sldj = (const float*)d_in[2];
  const float* lp   = (const float*)d_in[3];
  const float* mesh = (const float*)d_in[4];
  float* out = (float*)d_out;

  const int npts   = in_sizes[0] / DIM;
  const int npairs = npts * 2;
  const int block  = 256;
  int grid = 2048;
  const int needed = (npairs + block - 1) / block;
  if (needed < grid) grid = needed;

  hipLaunchKernelGGL(nll_kernel, dim3(grid), dim3(block), 0, stream,
                     x, pdj, sldj, lp, mesh, out, npts, npairs);
}